// Round 7
// baseline (1034.136 us; speedup 1.0000x reference)
//
#include <hip/hip_runtime.h>
#include <hip/hip_bf16.h>
#include <math.h>

typedef __bf16 bf16;
typedef __bf16 bf16x8 __attribute__((ext_vector_type(8)));
typedef float  f32x4  __attribute__((ext_vector_type(4)));

// async global->LDS, 16 B per lane; LDS dest = wave-uniform base + lane*16
__device__ __forceinline__ void load16_lds(const bf16* g, bf16* l) {
    __builtin_amdgcn_global_load_lds(
        (__attribute__((address_space(1))) void*)(g),
        (__attribute__((address_space(3))) void*)(l), 16, 0, 0);
}

// ---------------- fused weight converts (19 fp32 arrays -> bf16 shadows) ----------------
struct ConvArgs {
    const float* src[19];
    bf16* dst[19];
    int n[19];
    int bstart[20];
};
__global__ __launch_bounds__(256) void convert_many(ConvArgs a) {
    int blk = blockIdx.x;
    int s = 0;
    while (blk >= a.bstart[s + 1]) s++;
    const float* src = a.src[s];
    bf16* dst = a.dst[s];
    int n = a.n[s];
    int i0 = (blk - a.bstart[s]) * 2048;
#pragma unroll
    for (int e = 0; e < 8; e++) {
        int i = i0 + threadIdx.x + e * 256;
        if (i < n) dst[i] = (bf16)src[i];
    }
}

__global__ void zero_kernel(bf16* dst, int n) {
    int i = blockIdx.x * blockDim.x + threadIdx.x;
    if (i < n) dst[i] = (bf16)0.0f;
}

// ---------------- LayerNorm (fp32 math, templated input dtype) ----------------
template<class XT>
__global__ __launch_bounds__(256) void ln_kernel(
    const XT* __restrict__ X, const bf16* __restrict__ w,
    const bf16* __restrict__ b, bf16* __restrict__ out)
{
    const int C = 1024;
    const int row = blockIdx.x;
    const int tid = threadIdx.x;
    const XT* xr = X + (size_t)row * C;
    float x0 = (float)xr[tid * 4 + 0], x1 = (float)xr[tid * 4 + 1];
    float x2 = (float)xr[tid * 4 + 2], x3 = (float)xr[tid * 4 + 3];
    float s  = x0 + x1 + x2 + x3;
    float sq = x0*x0 + x1*x1 + x2*x2 + x3*x3;
#pragma unroll
    for (int off = 32; off >= 1; off >>= 1) {
        s  += __shfl_xor(s,  off, 64);
        sq += __shfl_xor(sq, off, 64);
    }
    __shared__ float red[8];
    int wave = tid >> 6;
    if ((tid & 63) == 0) { red[wave] = s; red[4 + wave] = sq; }
    __syncthreads();
    float ts = red[0] + red[1] + red[2] + red[3];
    float tq = red[4] + red[5] + red[6] + red[7];
    float mean = ts * (1.0f / C);
    float var  = tq * (1.0f / C) - mean * mean;
    float rstd = rsqrtf(var + 1e-5f);
    float w0 = (float)w[tid*4+0], w1 = (float)w[tid*4+1], w2 = (float)w[tid*4+2], w3 = (float)w[tid*4+3];
    float b0 = (float)b[tid*4+0], b1 = (float)b[tid*4+1], b2 = (float)b[tid*4+2], b3 = (float)b[tid*4+3];
    bf16* orow = out + (size_t)row * C + tid * 4;
    orow[0] = (bf16)((x0 - mean) * rstd * w0 + b0);
    orow[1] = (bf16)((x1 - mean) * rstd * w1 + b1);
    orow[2] = (bf16)((x2 - mean) * rstd * w2 + b2);
    orow[3] = (bf16)((x3 - mean) * rstd * w3 + b3);
}

// ---------------- GEMM v3: A reg-dbuf (prefetch dist 1), B LDS-dbuf ----------------
// out = act((A[M,K] @ W[N,K]^T + bias)*scale) + resid
// OMODE 0: normal; 1: V-transpose into [bh][d][1536]; 2: fused QKV split (N=3072).
// K must be a multiple of 128 (true: 256, 1024, 4096).
template<int ACT, int OMODE, class RT, class OT>
__global__ __launch_bounds__(256) void gemm_kernel(
    const bf16* __restrict__ A, const bf16* __restrict__ W,
    const bf16* __restrict__ bias, const RT* __restrict__ resid,
    OT* __restrict__ out, bf16* __restrict__ out_k, bf16* __restrict__ out_v,
    int M, int N, int K, float scale)
{
    __shared__ __align__(16) bf16 Bs[2][16 * 512];   // [buf][nsub*2+kk][512]
    const int tid = threadIdx.x;
    const int wave = tid >> 6, lane = tid & 63;
    const int lane15 = lane & 15, quad = lane >> 4;
    const int m0 = blockIdx.x * 128;
    const int n0 = blockIdx.y * 128;
    const int wm0 = (wave >> 1) * 64;
    const int wn0 = (wave & 1) * 64;
    f32x4 acc[4][4] = {};

    // B staging pointers: this wave stages n-subtiles {2w, 2w+1}
    const bf16* wp0 = W + (size_t)(n0 + (2 * wave)     * 16 + lane15) * K + quad * 8;
    const bf16* wp1 = W + (size_t)(n0 + (2 * wave + 1) * 16 + lane15) * K + quad * 8;

    // A fragment row pointers (4 m-subtiles), clamped
    const bf16* ap[4];
#pragma unroll
    for (int t = 0; t < 4; t++) {
        int r = m0 + wm0 + t * 16 + lane15;
        if (r > M - 1) r = M - 1;
        ap[t] = A + (size_t)r * K + quad * 8;
    }

    bf16x8 af[2][2][4];   // [phase][kk][mt]

    // prologue: phase-0 data for k0=0
#pragma unroll
    for (int kk = 0; kk < 2; kk++) {
#pragma unroll
        for (int t = 0; t < 4; t++)
            af[0][kk][t] = *(const bf16x8*)(ap[t] + kk * 32);
        load16_lds(wp0 + kk * 32, &Bs[0][((2 * wave)     * 2 + kk) * 512]);
        load16_lds(wp1 + kk * 32, &Bs[0][((2 * wave + 1) * 2 + kk) * 512]);
    }

    for (int k0 = 0; k0 < K; k0 += 128) {
        // ---- phase 0: compute k0 with af[0]/Bs[0]; prefetch k0+64 into af[1]/Bs[1]
        __syncthreads();   // drains loads issued a full phase ago
#pragma unroll
        for (int kk = 0; kk < 2; kk++) {
#pragma unroll
            for (int t = 0; t < 4; t++)
                af[1][kk][t] = *(const bf16x8*)(ap[t] + k0 + 64 + kk * 32);
            load16_lds(wp0 + k0 + 64 + kk * 32, &Bs[1][((2 * wave)     * 2 + kk) * 512]);
            load16_lds(wp1 + k0 + 64 + kk * 32, &Bs[1][((2 * wave + 1) * 2 + kk) * 512]);
        }
#pragma unroll
        for (int kk = 0; kk < 2; kk++) {
            bf16x8 bfr[4];
#pragma unroll
            for (int t = 0; t < 4; t++)
                bfr[t] = *(const bf16x8*)(&Bs[0][(((wn0 >> 4) + t) * 2 + kk) * 512 + lane * 8]);
#pragma unroll
            for (int mt = 0; mt < 4; mt++)
#pragma unroll
                for (int nt = 0; nt < 4; nt++)
                    acc[mt][nt] = __builtin_amdgcn_mfma_f32_16x16x32_bf16(
                        af[0][kk][mt], bfr[nt], acc[mt][nt], 0, 0, 0);
        }
        // ---- phase 1: compute k0+64 with af[1]/Bs[1]; prefetch k0+128 into af[0]/Bs[0]
        __syncthreads();
        if (k0 + 128 < K) {
#pragma unroll
            for (int kk = 0; kk < 2; kk++) {
#pragma unroll
                for (int t = 0; t < 4; t++)
                    af[0][kk][t] = *(const bf16x8*)(ap[t] + k0 + 128 + kk * 32);
                load16_lds(wp0 + k0 + 128 + kk * 32, &Bs[0][((2 * wave)     * 2 + kk) * 512]);
                load16_lds(wp1 + k0 + 128 + kk * 32, &Bs[0][((2 * wave + 1) * 2 + kk) * 512]);
            }
        }
#pragma unroll
        for (int kk = 0; kk < 2; kk++) {
            bf16x8 bfr[4];
#pragma unroll
            for (int t = 0; t < 4; t++)
                bfr[t] = *(const bf16x8*)(&Bs[1][(((wn0 >> 4) + t) * 2 + kk) * 512 + lane * 8]);
#pragma unroll
            for (int mt = 0; mt < 4; mt++)
#pragma unroll
                for (int nt = 0; nt < 4; nt++)
                    acc[mt][nt] = __builtin_amdgcn_mfma_f32_16x16x32_bf16(
                        af[1][kk][mt], bfr[nt], acc[mt][nt], 0, 0, 0);
        }
    }

    // epilogue: C/D layout col=lane&15, row=quad*4+reg
#pragma unroll
    for (int mt = 0; mt < 4; mt++) {
#pragma unroll
        for (int r = 0; r < 4; r++) {
            int gm = m0 + wm0 + mt * 16 + quad * 4 + r;
            if (gm >= M) continue;
#pragma unroll
            for (int nt = 0; nt < 4; nt++) {
                int gn = n0 + wn0 + nt * 16 + lane15;
                float v = acc[mt][nt][r];
                if (bias) v += (float)bias[gn];
                if (OMODE == 2) { if (gn < 2048) v *= scale; }
                else v *= scale;
                if (ACT == 1) v = 0.5f * v * (1.0f + erff(v * 0.70710678118f));
                if (OMODE == 1) {
                    int bb = gm / 1500;
                    int ss = gm - bb * 1500;
                    int hh = gn >> 6, dd = gn & 63;
                    ((bf16*)out)[(((size_t)bb * 16 + hh) * 64 + dd) * 1536 + ss] = (bf16)v;
                } else if (OMODE == 2) {
                    if (gn < 1024) {
                        ((bf16*)out)[(size_t)gm * 1024 + gn] = (bf16)v;            // q
                    } else if (gn < 2048) {
                        out_k[(size_t)gm * 1024 + (gn - 1024)] = (bf16)v;          // k
                    } else {
                        int gg = gn - 2048;
                        int bb = gm / 1500;
                        int ss = gm - bb * 1500;
                        int hh = gg >> 6, dd = gg & 63;
                        out_v[(((size_t)bb * 16 + hh) * 64 + dd) * 1536 + ss] = (bf16)v;  // v^T
                    }
                } else {
                    if (resid) v += (float)resid[(size_t)gm * N + gn];
                    out[(size_t)gm * N + gn] = (OT)v;
                }
            }
        }
    }
}

// ---------------- Flash attention, fragment-order staging (verified r5) ----------------
__global__ __launch_bounds__(256) void flash_attn_kernel(
    const bf16* __restrict__ Q, const bf16* __restrict__ Km,
    const bf16* __restrict__ Vt, bf16* __restrict__ O)
{
    const int S = 1500, C = 1024, SP = 1536;
    const int LDP = 72;
    __shared__ __align__(16) bf16 Ks[8 * 512];
    __shared__ __align__(16) bf16 Vs[8 * 512];
    __shared__ __align__(16) bf16 Ps[4 * 16 * LDP];
    const int tid = threadIdx.x;
    const int wave = tid >> 6, lane = tid & 63;
    const int lane15 = lane & 15, quad = lane >> 4;
    const int bh = blockIdx.y;
    const int q0 = blockIdx.x * 64;
    const size_t headoff = (size_t)(bh >> 4) * S * C + (size_t)(bh & 15) * 64;
    const size_t vtoff   = (size_t)bh * 64 * SP;

    bf16x8 qf[2];
    int qr = q0 + wave * 16 + lane15; if (qr > S - 1) qr = S - 1;
    qf[0] = *(const bf16x8*)(Q + headoff + (size_t)qr * C + quad * 8);
    qf[1] = *(const bf16x8*)(Q + headoff + (size_t)qr * C + 32 + quad * 8);

    const bf16* vbase = Vt + vtoff + (size_t)(wave * 16 + lane15) * SP + quad * 8;

    float m_run[4], l_run[4];
    f32x4 o_acc[4] = {};
#pragma unroll
    for (int r = 0; r < 4; r++) { m_run[r] = -1e30f; l_run[r] = 0.0f; }

    for (int kt = 0; kt < 24; kt++) {
        const int j0 = kt * 64;
        int kr = j0 + wave * 16 + lane15; if (kr > S - 1) kr = S - 1;
        const bf16* kbase = Km + headoff + (size_t)kr * C + quad * 8;
#pragma unroll
        for (int kk = 0; kk < 2; kk++) {
            load16_lds(kbase + kk * 32,      &Ks[(wave * 2 + kk) * 512]);
            load16_lds(vbase + j0 + kk * 32, &Vs[(wave * 2 + kk) * 512]);
        }
        __syncthreads();

        f32x4 s[4] = {};
#pragma unroll
        for (int kk = 0; kk < 2; kk++) {
#pragma unroll
            for (int nt = 0; nt < 4; nt++) {
                bf16x8 kf = *(const bf16x8*)(&Ks[(nt * 2 + kk) * 512 + lane * 8]);
                s[nt] = __builtin_amdgcn_mfma_f32_16x16x32_bf16(qf[kk], kf, s[nt], 0, 0, 0);
            }
        }
#pragma unroll
        for (int nt = 0; nt < 4; nt++) {
            if (j0 + nt * 16 + lane15 >= S) {
#pragma unroll
                for (int r = 0; r < 4; r++) s[nt][r] = -1e30f;
            }
        }
        float mnew[4], alpha[4];
#pragma unroll
        for (int r = 0; r < 4; r++) {
            float tm = fmaxf(fmaxf(s[0][r], s[1][r]), fmaxf(s[2][r], s[3][r]));
#pragma unroll
            for (int off = 1; off < 16; off <<= 1) tm = fmaxf(tm, __shfl_xor(tm, off, 64));
            mnew[r]  = fmaxf(m_run[r], tm);
            alpha[r] = __expf(m_run[r] - mnew[r]);
            float ps = 0.0f;
#pragma unroll
            for (int nt = 0; nt < 4; nt++) {
                float p = __expf(s[nt][r] - mnew[r]);
                s[nt][r] = p;
                ps += p;
            }
#pragma unroll
            for (int off = 1; off < 16; off <<= 1) ps += __shfl_xor(ps, off, 64);
            l_run[r] = l_run[r] * alpha[r] + ps;
            m_run[r] = mnew[r];
        }
#pragma unroll
        for (int dt = 0; dt < 4; dt++)
#pragma unroll
            for (int r = 0; r < 4; r++) o_acc[dt][r] *= alpha[r];
#pragma unroll
        for (int nt = 0; nt < 4; nt++)
#pragma unroll
            for (int r = 0; r < 4; r++)
                Ps[wave * 16 * LDP + (quad * 4 + r) * LDP + nt * 16 + lane15] = (bf16)s[nt][r];
        __syncthreads();
#pragma unroll
        for (int kk = 0; kk < 2; kk++) {
            bf16x8 pf = *(const bf16x8*)(&Ps[wave * 16 * LDP + lane15 * LDP + kk * 32 + quad * 8]);
#pragma unroll
            for (int dt = 0; dt < 4; dt++) {
                bf16x8 vf = *(const bf16x8*)(&Vs[(dt * 2 + kk) * 512 + lane * 8]);
                o_acc[dt] = __builtin_amdgcn_mfma_f32_16x16x32_bf16(pf, vf, o_acc[dt], 0, 0, 0);
            }
        }
        __syncthreads();
    }

#pragma unroll
    for (int dt = 0; dt < 4; dt++) {
#pragma unroll
        for (int r = 0; r < 4; r++) {
            int row = q0 + wave * 16 + quad * 4 + r;
            if (row < S) {
                float v = o_acc[dt][r] / l_run[r];
                O[headoff + (size_t)row * C + dt * 16 + lane15] = (bf16)v;
            }
        }
    }
}

extern "C" void kernel_launch(void* const* d_in, const int* in_sizes, int n_in,
                              void* d_out, int out_size, void* d_ws, size_t ws_size,
                              hipStream_t stream) {
    float* out = (float*)d_out;
    const float* x_f32 = (const float*)d_in[0];
    const int M = 6000, Cc = 1024, F = 4096, Aa = 256;
    const size_t MC = (size_t)M * Cc;
    const size_t VT_ELEMS = (size_t)64 * 64 * 1536;
    bf16* ws = (bf16*)d_ws;

    bf16* h1   = ws;                         // [M,C]
    bf16* kbuf = ws + MC;                    // [M,C]
    bf16* Vt   = ws + 2 * MC;                // [64][64][1536]
    bf16* g    = ws + 2 * MC + VT_ELEMS;     // [M,F]
    bf16* q    = (bf16*)d_out;               // d_out spare half as bf16 scratch
    bf16* wv   = h1;                         // h1 dead after QKV
    bf16* x1   = q;                          // q dead after attention
    bf16* h2   = kbuf;                       // k dead after attention
    bf16* x2   = Vt;                         // Vt dead after attention
    bf16* aact = kbuf;                       // free after MLP1

    // weight shadows
    size_t off = 2 * MC + VT_ELEMS + (size_t)M * F;
    bf16* Wqkv = ws + off; off += (size_t)3 * 1024 * 1024;
    bf16* bqkv = ws + off; off += 3072;
    bf16* sWo  = ws + off; off += (size_t)1024 * 1024;
    bf16* sbo  = ws + off; off += 1024;
    bf16* slnw = ws + off; off += 1024;
    bf16* slnb = ws + off; off += 1024;
    bf16* sW1  = ws + off; off += (size_t)4096 * 1024;
    bf16* sb1  = ws + off; off += 4096;
    bf16* sW2  = ws + off; off += (size_t)1024 * 4096;
    bf16* sb2  = ws + off; off += 1024;
    bf16* sln2w = ws + off; off += 1024;
    bf16* sln2b = ws + off; off += 1024;
    bf16* sWds = ws + off; off += (size_t)256 * 1024;
    bf16* sbds = ws + off; off += 256;
    bf16* sWus = ws + off; off += (size_t)1024 * 256;
    bf16* sbus = ws + off; off += 1024;

    ConvArgs ca;
    const int srcidx[19] = {1, 3, 4, 2, 5, 6, 7, 8, 9, 10, 11, 12, 13, 14, 15, 16, 17, 18, 19};
    bf16* dsts[19] = {Wqkv, Wqkv + 1048576, Wqkv + 2097152, bqkv, bqkv + 2048,
                      sWo, sbo, slnw, slnb, sW1, sb1, sW2, sb2, sln2w, sln2b,
                      sWds, sbds, sWus, sbus};
    int bacc = 0;
    for (int i = 0; i < 19; i++) {
        ca.src[i] = (const float*)d_in[srcidx[i]];
        ca.dst[i] = dsts[i];
        ca.n[i] = in_sizes[srcidx[i]];
        ca.bstart[i] = bacc;
        bacc += (ca.n[i] + 2047) / 2048;
    }
    ca.bstart[19] = bacc;

    dim3 blk(256);
    convert_many<<<bacc, blk, 0, stream>>>(ca);
    zero_kernel<<<4, blk, 0, stream>>>(bqkv + 1024, 1024);   // no k-bias

    const float scale = 0.35355339059327373f;  // 64^-0.25
    dim3 gQKV(47, 24);  // N=3072
    dim3 gN(47, 8);     // N=1024
    dim3 gF(47, 32);    // N=4096
    dim3 gA(47, 2);     // N=256

    ln_kernel<float><<<M, blk, 0, stream>>>(x_f32, slnw, slnb, h1);
    gemm_kernel<0, 2, bf16, bf16><<<gQKV, blk, 0, stream>>>(
        h1, Wqkv, bqkv, (const bf16*)nullptr, q, kbuf, Vt, M, 3072, Cc, scale);
    dim3 ga(24, 64);
    flash_attn_kernel<<<ga, blk, 0, stream>>>(q, kbuf, Vt, wv);
    gemm_kernel<0, 0, float, bf16><<<gN, blk, 0, stream>>>(
        wv, sWo, sbo, x_f32, x1, nullptr, nullptr, M, Cc, Cc, 1.0f);
    ln_kernel<bf16><<<M, blk, 0, stream>>>(x1, sln2w, sln2b, h2);
    gemm_kernel<1, 0, bf16, bf16><<<gF, blk, 0, stream>>>(
        h2, sW1, sb1, (const bf16*)nullptr, g, nullptr, nullptr, M, F, Cc, 1.0f);
    gemm_kernel<0, 0, bf16, bf16><<<gN, blk, 0, stream>>>(
        g, sW2, sb2, x1, x2, nullptr, nullptr, M, Cc, F, 1.0f);
    gemm_kernel<1, 0, bf16, bf16><<<gA, blk, 0, stream>>>(
        x2, sWds, sbds, (const bf16*)nullptr, aact, nullptr, nullptr, M, Aa, Cc, 1.0f);
    gemm_kernel<0, 0, bf16, float><<<gN, blk, 0, stream>>>(
        aact, sWus, sbus, x2, out, nullptr, nullptr, M, Cc, Aa, 1.0f);
}

// Round 8
// 855.812 us; speedup vs baseline: 1.2084x; 1.2084x over previous
//
#include <hip/hip_runtime.h>
#include <hip/hip_bf16.h>
#include <math.h>

typedef __bf16 bf16;
typedef __bf16 bf16x8 __attribute__((ext_vector_type(8)));
typedef float  f32x4  __attribute__((ext_vector_type(4)));

__device__ __forceinline__ bf16x8 zero8() { bf16x8 z = {}; return z; }

// async global->LDS, 16 B per lane; LDS dest = wave-uniform base + lane*16
__device__ __forceinline__ void load16_lds(const bf16* g, bf16* l) {
    __builtin_amdgcn_global_load_lds(
        (__attribute__((address_space(1))) void*)(g),
        (__attribute__((address_space(3))) void*)(l), 16, 0, 0);
}

// tanh-form GELU (max abs err vs exact erf-GELU ~7e-4)
__device__ __forceinline__ float gelu_f(float x) {
    float u = 1.5957691216057308f * (x + 0.044715f * x * x * x);  // 2*sqrt(2/pi)*(...)
    float e = __expf(u);
    float th = 1.0f - 2.0f / (1.0f + e);
    return 0.5f * x * (1.0f + th);
}

// ---------------- fused weight converts ----------------
struct ConvArgs {
    const float* src[19];
    bf16* dst[19];
    int n[19];
    int bstart[20];
};
__global__ __launch_bounds__(256) void convert_many(ConvArgs a) {
    int blk = blockIdx.x;
    int s = 0;
    while (blk >= a.bstart[s + 1]) s++;
    const float* src = a.src[s];
    bf16* dst = a.dst[s];
    int n = a.n[s];
    int i0 = (blk - a.bstart[s]) * 2048;
#pragma unroll
    for (int e = 0; e < 8; e++) {
        int i = i0 + threadIdx.x + e * 256;
        if (i < n) dst[i] = (bf16)src[i];
    }
}

__global__ void zero_kernel(bf16* dst, int n) {
    int i = blockIdx.x * blockDim.x + threadIdx.x;
    if (i < n) dst[i] = (bf16)0.0f;
}

// ---------------- LayerNorm ----------------
template<class XT>
__global__ __launch_bounds__(256) void ln_kernel(
    const XT* __restrict__ X, const bf16* __restrict__ w,
    const bf16* __restrict__ b, bf16* __restrict__ out)
{
    const int C = 1024;
    const int row = blockIdx.x;
    const int tid = threadIdx.x;
    const XT* xr = X + (size_t)row * C;
    float x0 = (float)xr[tid * 4 + 0], x1 = (float)xr[tid * 4 + 1];
    float x2 = (float)xr[tid * 4 + 2], x3 = (float)xr[tid * 4 + 3];
    float s  = x0 + x1 + x2 + x3;
    float sq = x0*x0 + x1*x1 + x2*x2 + x3*x3;
#pragma unroll
    for (int off = 32; off >= 1; off >>= 1) {
        s  += __shfl_xor(s,  off, 64);
        sq += __shfl_xor(sq, off, 64);
    }
    __shared__ float red[8];
    int wave = tid >> 6;
    if ((tid & 63) == 0) { red[wave] = s; red[4 + wave] = sq; }
    __syncthreads();
    float ts = red[0] + red[1] + red[2] + red[3];
    float tq = red[4] + red[5] + red[6] + red[7];
    float mean = ts * (1.0f / C);
    float var  = tq * (1.0f / C) - mean * mean;
    float rstd = rsqrtf(var + 1e-5f);
    float w0 = (float)w[tid*4+0], w1 = (float)w[tid*4+1], w2 = (float)w[tid*4+2], w3 = (float)w[tid*4+3];
    float b0 = (float)b[tid*4+0], b1 = (float)b[tid*4+1], b2 = (float)b[tid*4+2], b3 = (float)b[tid*4+3];
    bf16* orow = out + (size_t)row * C + tid * 4;
    orow[0] = (bf16)((x0 - mean) * rstd * w0 + b0);
    orow[1] = (bf16)((x1 - mean) * rstd * w1 + b1);
    orow[2] = (bf16)((x2 - mean) * rstd * w2 + b2);
    orow[3] = (bf16)((x3 - mean) * rstd * w3 + b3);
}

// ---------------- GEMM (r5 core + XCD-banded swizzle) ----------------
// out = act((A[M,K] @ W[N,K]^T + bias)*scale) + resid
// OMODE 0: normal; 2: fused QKV split (N=3072, scale only on first 2048 cols).
// 1-D grid of 8*mQ*nQ blocks. XCD banding: lin%8 -> (xm in 0..3, xn in 0..1);
// block covers m-tile (xm + 4j), n-tile (xn + 2i) -> per-XCD L2 working set ~3-4 MB.
template<int ACT, int OMODE, class RT, class OT>
__global__ __launch_bounds__(256) void gemm_kernel(
    const bf16* __restrict__ A, const bf16* __restrict__ W,
    const bf16* __restrict__ bias, const RT* __restrict__ resid,
    OT* __restrict__ out, bf16* __restrict__ out_k, bf16* __restrict__ out_v,
    int M, int N, int K, float scale, int gmT, int gnT, int mQ)
{
    const int lin = blockIdx.x;
    const int xcd = lin & 7;
    const int t_  = lin >> 3;
    const int mt_ = (xcd & 3) + 4 * (t_ % mQ);
    const int nt_ = (xcd >> 2) + 2 * (t_ / mQ);
    if (mt_ >= gmT || nt_ >= gnT) return;
    const int m0 = mt_ * 128;
    const int n0 = nt_ * 128;

    __shared__ __align__(16) bf16 As[16 * 512];   // chunk (msub*2+kk): 1 KB each
    __shared__ __align__(16) bf16 Bs[16 * 512];
    const int tid = threadIdx.x;
    const int wave = tid >> 6, lane = tid & 63;
    const int lane15 = lane & 15, quad = lane >> 4;
    const int wm0 = (wave >> 1) * 64;
    const int wn0 = (wave & 1) * 64;
    f32x4 acc[4][4] = {};

    int ra0 = m0 + (2 * wave)     * 16 + lane15; if (ra0 > M - 1) ra0 = M - 1;
    int ra1 = m0 + (2 * wave + 1) * 16 + lane15; if (ra1 > M - 1) ra1 = M - 1;
    const int rb0 = n0 + (2 * wave)     * 16 + lane15;
    const int rb1 = n0 + (2 * wave + 1) * 16 + lane15;
    const bf16* a0 = A + (size_t)ra0 * K + quad * 8;
    const bf16* a1 = A + (size_t)ra1 * K + quad * 8;
    const bf16* w0 = W + (size_t)rb0 * K + quad * 8;
    const bf16* w1 = W + (size_t)rb1 * K + quad * 8;

    for (int k0 = 0; k0 < K; k0 += 64) {
#pragma unroll
        for (int kk = 0; kk < 2; kk++) {
            load16_lds(a0 + k0 + kk * 32, &As[((2 * wave)     * 2 + kk) * 512]);
            load16_lds(a1 + k0 + kk * 32, &As[((2 * wave + 1) * 2 + kk) * 512]);
            load16_lds(w0 + k0 + kk * 32, &Bs[((2 * wave)     * 2 + kk) * 512]);
            load16_lds(w1 + k0 + kk * 32, &Bs[((2 * wave + 1) * 2 + kk) * 512]);
        }
        __syncthreads();
#pragma unroll
        for (int kk = 0; kk < 2; kk++) {
            bf16x8 af[4], bfr[4];
#pragma unroll
            for (int t = 0; t < 4; t++) {
                af[t]  = *(const bf16x8*)(&As[(((wm0 >> 4) + t) * 2 + kk) * 512 + lane * 8]);
                bfr[t] = *(const bf16x8*)(&Bs[(((wn0 >> 4) + t) * 2 + kk) * 512 + lane * 8]);
            }
#pragma unroll
            for (int mt = 0; mt < 4; mt++)
#pragma unroll
                for (int nt = 0; nt < 4; nt++)
                    acc[mt][nt] = __builtin_amdgcn_mfma_f32_16x16x32_bf16(
                        af[mt], bfr[nt], acc[mt][nt], 0, 0, 0);
        }
        __syncthreads();
    }

    // epilogue: C/D layout col=lane&15, row=quad*4+reg
#pragma unroll
    for (int mt = 0; mt < 4; mt++) {
#pragma unroll
        for (int r = 0; r < 4; r++) {
            int gm = m0 + wm0 + mt * 16 + quad * 4 + r;
            if (gm >= M) continue;
#pragma unroll
            for (int nt = 0; nt < 4; nt++) {
                int gn = n0 + wn0 + nt * 16 + lane15;
                float v = acc[mt][nt][r];
                if (bias) v += (float)bias[gn];
                if (OMODE == 2) { if (gn < 2048) v *= scale; }
                else v *= scale;
                if (ACT == 1) v = gelu_f(v);
                if (OMODE == 2) {
                    if (gn < 1024) {
                        ((bf16*)out)[(size_t)gm * 1024 + gn] = (bf16)v;            // q
                    } else if (gn < 2048) {
                        out_k[(size_t)gm * 1024 + (gn - 1024)] = (bf16)v;          // k
                    } else {
                        int gg = gn - 2048;
                        int bb = gm / 1500;
                        int ss = gm - bb * 1500;
                        int hh = gg >> 6, dd = gg & 63;
                        out_v[(((size_t)bb * 16 + hh) * 64 + dd) * 1536 + ss] = (bf16)v;  // v^T
                    }
                } else {
                    if (resid) v += (float)resid[(size_t)gm * N + gn];
                    out[(size_t)gm * N + gn] = (OT)v;
                }
            }
        }
    }
}

// ---------------- Flash attention (verified r5) ----------------
__global__ __launch_bounds__(256) void flash_attn_kernel(
    const bf16* __restrict__ Q, const bf16* __restrict__ Km,
    const bf16* __restrict__ Vt, bf16* __restrict__ O)
{
    const int S = 1500, C = 1024, SP = 1536;
    const int LDP = 72;
    __shared__ __align__(16) bf16 Ks[8 * 512];
    __shared__ __align__(16) bf16 Vs[8 * 512];
    __shared__ __align__(16) bf16 Ps[4 * 16 * LDP];
    const int tid = threadIdx.x;
    const int wave = tid >> 6, lane = tid & 63;
    const int lane15 = lane & 15, quad = lane >> 4;
    const int bh = blockIdx.y;
    const int q0 = blockIdx.x * 64;
    const size_t headoff = (size_t)(bh >> 4) * S * C + (size_t)(bh & 15) * 64;
    const size_t vtoff   = (size_t)bh * 64 * SP;

    bf16x8 qf[2];
    int qr = q0 + wave * 16 + lane15; if (qr > S - 1) qr = S - 1;
    qf[0] = *(const bf16x8*)(Q + headoff + (size_t)qr * C + quad * 8);
    qf[1] = *(const bf16x8*)(Q + headoff + (size_t)qr * C + 32 + quad * 8);

    const bf16* vbase = Vt + vtoff + (size_t)(wave * 16 + lane15) * SP + quad * 8;

    float m_run[4], l_run[4];
    f32x4 o_acc[4] = {};
#pragma unroll
    for (int r = 0; r < 4; r++) { m_run[r] = -1e30f; l_run[r] = 0.0f; }

    for (int kt = 0; kt < 24; kt++) {
        const int j0 = kt * 64;
        int kr = j0 + wave * 16 + lane15; if (kr > S - 1) kr = S - 1;
        const bf16* kbase = Km + headoff + (size_t)kr * C + quad * 8;
#pragma unroll
        for (int kk = 0; kk < 2; kk++) {
            load16_lds(kbase + kk * 32,      &Ks[(wave * 2 + kk) * 512]);
            load16_lds(vbase + j0 + kk * 32, &Vs[(wave * 2 + kk) * 512]);
        }
        __syncthreads();

        f32x4 s[4] = {};
#pragma unroll
        for (int kk = 0; kk < 2; kk++) {
#pragma unroll
            for (int nt = 0; nt < 4; nt++) {
                bf16x8 kf = *(const bf16x8*)(&Ks[(nt * 2 + kk) * 512 + lane * 8]);
                s[nt] = __builtin_amdgcn_mfma_f32_16x16x32_bf16(qf[kk], kf, s[nt], 0, 0, 0);
            }
        }
#pragma unroll
        for (int nt = 0; nt < 4; nt++) {
            if (j0 + nt * 16 + lane15 >= S) {
#pragma unroll
                for (int r = 0; r < 4; r++) s[nt][r] = -1e30f;
            }
        }
        float mnew[4], alpha[4];
#pragma unroll
        for (int r = 0; r < 4; r++) {
            float tm = fmaxf(fmaxf(s[0][r], s[1][r]), fmaxf(s[2][r], s[3][r]));
#pragma unroll
            for (int off = 1; off < 16; off <<= 1) tm = fmaxf(tm, __shfl_xor(tm, off, 64));
            mnew[r]  = fmaxf(m_run[r], tm);
            alpha[r] = __expf(m_run[r] - mnew[r]);
            float ps = 0.0f;
#pragma unroll
            for (int nt = 0; nt < 4; nt++) {
                float p = __expf(s[nt][r] - mnew[r]);
                s[nt][r] = p;
                ps += p;
            }
#pragma unroll
            for (int off = 1; off < 16; off <<= 1) ps += __shfl_xor(ps, off, 64);
            l_run[r] = l_run[r] * alpha[r] + ps;
            m_run[r] = mnew[r];
        }
#pragma unroll
        for (int dt = 0; dt < 4; dt++)
#pragma unroll
            for (int r = 0; r < 4; r++) o_acc[dt][r] *= alpha[r];
#pragma unroll
        for (int nt = 0; nt < 4; nt++)
#pragma unroll
            for (int r = 0; r < 4; r++)
                Ps[wave * 16 * LDP + (quad * 4 + r) * LDP + nt * 16 + lane15] = (bf16)s[nt][r];
        __syncthreads();
#pragma unroll
        for (int kk = 0; kk < 2; kk++) {
            bf16x8 pf = *(const bf16x8*)(&Ps[wave * 16 * LDP + lane15 * LDP + kk * 32 + quad * 8]);
#pragma unroll
            for (int dt = 0; dt < 4; dt++) {
                bf16x8 vf = *(const bf16x8*)(&Vs[(dt * 2 + kk) * 512 + lane * 8]);
                o_acc[dt] = __builtin_amdgcn_mfma_f32_16x16x32_bf16(pf, vf, o_acc[dt], 0, 0, 0);
            }
        }
        __syncthreads();
    }

#pragma unroll
    for (int dt = 0; dt < 4; dt++) {
#pragma unroll
        for (int r = 0; r < 4; r++) {
            int row = q0 + wave * 16 + quad * 4 + r;
            if (row < S) {
                float v = o_acc[dt][r] / l_run[r];
                O[headoff + (size_t)row * C + dt * 16 + lane15] = (bf16)v;
            }
        }
    }
}

extern "C" void kernel_launch(void* const* d_in, const int* in_sizes, int n_in,
                              void* d_out, int out_size, void* d_ws, size_t ws_size,
                              hipStream_t stream) {
    float* out = (float*)d_out;
    const float* x_f32 = (const float*)d_in[0];
    const int M = 6000, Cc = 1024, F = 4096, Aa = 256;
    const size_t MC = (size_t)M * Cc;
    const size_t VT_ELEMS = (size_t)64 * 64 * 1536;
    bf16* ws = (bf16*)d_ws;

    bf16* h1   = ws;                         // [M,C]
    bf16* kbuf = ws + MC;                    // [M,C]
    bf16* Vt   = ws + 2 * MC;                // [64][64][1536]
    bf16* g    = ws + 2 * MC + VT_ELEMS;     // [M,F]
    bf16* q    = (bf16*)d_out;               // d_out spare half as bf16 scratch
    bf16* wv   = h1;
    bf16* x1   = q;
    bf16* h2   = kbuf;
    bf16* x2   = Vt;
    bf16* aact = kbuf;

    size_t off = 2 * MC + VT_ELEMS + (size_t)M * F;
    bf16* Wqkv = ws + off; off += (size_t)3 * 1024 * 1024;
    bf16* bqkv = ws + off; off += 3072;
    bf16* sWo  = ws + off; off += (size_t)1024 * 1024;
    bf16* sbo  = ws + off; off += 1024;
    bf16* slnw = ws + off; off += 1024;
    bf16* slnb = ws + off; off += 1024;
    bf16* sW1  = ws + off; off += (size_t)4096 * 1024;
    bf16* sb1  = ws + off; off += 4096;
    bf16* sW2  = ws + off; off += (size_t)1024 * 4096;
    bf16* sb2  = ws + off; off += 1024;
    bf16* sln2w = ws + off; off += 1024;
    bf16* sln2b = ws + off; off += 1024;
    bf16* sWds = ws + off; off += (size_t)256 * 1024;
    bf16* sbds = ws + off; off += 256;
    bf16* sWus = ws + off; off += (size_t)1024 * 256;
    bf16* sbus = ws + off; off += 1024;

    ConvArgs ca;
    const int srcidx[19] = {1, 3, 4, 2, 5, 6, 7, 8, 9, 10, 11, 12, 13, 14, 15, 16, 17, 18, 19};
    bf16* dsts[19] = {Wqkv, Wqkv + 1048576, Wqkv + 2097152, bqkv, bqkv + 2048,
                      sWo, sbo, slnw, slnb, sW1, sb1, sW2, sb2, sln2w, sln2b,
                      sWds, sbds, sWus, sbus};
    int bacc = 0;
    for (int i = 0; i < 19; i++) {
        ca.src[i] = (const float*)d_in[srcidx[i]];
        ca.dst[i] = dsts[i];
        ca.n[i] = in_sizes[srcidx[i]];
        ca.bstart[i] = bacc;
        bacc += (ca.n[i] + 2047) / 2048;
    }
    ca.bstart[19] = bacc;

    dim3 blk(256);
    convert_many<<<bacc, blk, 0, stream>>>(ca);
    zero_kernel<<<4, blk, 0, stream>>>(bqkv + 1024, 1024);   // no k-bias

    const float scale = 0.35355339059327373f;  // 64^-0.25
    const int gmT = 47, mQ = 12;               // ceil(47/4)
    auto grid_for = [&](int gnT) { int nQ = (gnT + 1) >> 1; return dim3(8 * mQ * nQ); };

    ln_kernel<float><<<M, blk, 0, stream>>>(x_f32, slnw, slnb, h1);
    gemm_kernel<0, 2, bf16, bf16><<<grid_for(24), blk, 0, stream>>>(
        h1, Wqkv, bqkv, (const bf16*)nullptr, q, kbuf, Vt, M, 3072, Cc, scale, gmT, 24, mQ);
    dim3 ga(24, 64);
    flash_attn_kernel<<<ga, blk, 0, stream>>>(q, kbuf, Vt, wv);
    gemm_kernel<0, 0, float, bf16><<<grid_for(8), blk, 0, stream>>>(
        wv, sWo, sbo, x_f32, x1, nullptr, nullptr, M, Cc, Cc, 1.0f, gmT, 8, mQ);
    ln_kernel<bf16><<<M, blk, 0, stream>>>(x1, sln2w, sln2b, h2);
    gemm_kernel<1, 0, bf16, bf16><<<grid_for(32), blk, 0, stream>>>(
        h2, sW1, sb1, (const bf16*)nullptr, g, nullptr, nullptr, M, F, Cc, 1.0f, gmT, 32, mQ);
    gemm_kernel<0, 0, bf16, bf16><<<grid_for(8), blk, 0, stream>>>(
        g, sW2, sb2, x1, x2, nullptr, nullptr, M, Cc, F, 1.0f, gmT, 8, mQ);
    gemm_kernel<1, 0, bf16, bf16><<<grid_for(2), blk, 0, stream>>>(
        x2, sWds, sbds, (const bf16*)nullptr, aact, nullptr, nullptr, M, Aa, Cc, 1.0f, gmT, 2, mQ);
    gemm_kernel<0, 0, bf16, float><<<grid_for(8), blk, 0, stream>>>(
        aact, sWus, sbus, x2, out, nullptr, nullptr, M, Cc, Aa, 1.0f, gmT, 8, mQ);
}